// Round 1
// baseline (467.441 us; speedup 1.0000x reference)
//
#include <hip/hip_runtime.h>
#include <math.h>

// Problem constants from the reference:
//   B=32, P=3, D=300, N=2048
// Inputs:  x,y  [B,P,D,N] f32 (row-major, n fastest)
// Output:  out  [B, P*N, 3] f32, per (b,p,n): {cos, l2, l1} over the D axis.
//
// One thread per (b,p,n). Lane i handles n0+i -> each d-row load is a fully
// coalesced 256B wave transaction. Memory-bound: 472 MB read / ~75 us floor.

constexpr int kB = 32;
constexpr int kP = 3;
constexpr int kD = 300;
constexpr int kN = 2048;

__global__ __launch_bounds__(256) void sim_measure_kernel(
    const float* __restrict__ x,
    const float* __restrict__ y,
    float* __restrict__ out)
{
    const int tid = blockIdx.x * 256 + threadIdx.x;
    const int total = kB * kP * kN;
    if (tid >= total) return;

    const int n  = tid & (kN - 1);   // N = 2048 = 2^11
    const int bp = tid >> 11;        // fused (b*P + p) index

    const size_t base = (size_t)bp * kD * kN + n;
    const float* __restrict__ xp = x + base;
    const float* __restrict__ yp = y + base;

    float dot = 0.f, xx = 0.f, yy = 0.f, l2s = 0.f, l1 = 0.f;

    #pragma unroll 4
    for (int d = 0; d < kD; ++d) {
        const float xv = xp[(size_t)d * kN];
        const float yv = yp[(size_t)d * kN];
        dot = fmaf(xv, yv, dot);
        xx  = fmaf(xv, xv, xx);
        yy  = fmaf(yv, yv, yy);
        const float df = xv - yv;
        l2s = fmaf(df, df, l2s);
        l1 += fabsf(df);
    }

    // Match reference math exactly: cos = dot / (sqrt(xx) * sqrt(yy))
    const float cosv = dot / (sqrtf(xx) * sqrtf(yy));
    const float l2v  = sqrtf(l2s);

    // out[(bp*N + n)*3 + k]; tid == bp*N + n
    const size_t o = (size_t)tid * 3;
    out[o + 0] = cosv;
    out[o + 1] = l2v;
    out[o + 2] = l1;
}

extern "C" void kernel_launch(void* const* d_in, const int* in_sizes, int n_in,
                              void* d_out, int out_size, void* d_ws, size_t ws_size,
                              hipStream_t stream)
{
    const float* x = (const float*)d_in[0];
    const float* y = (const float*)d_in[1];
    float* out = (float*)d_out;

    const int total = kB * kP * kN;          // 196,608 threads
    const int block = 256;
    const int grid  = (total + block - 1) / block;  // 768 blocks

    sim_measure_kernel<<<grid, block, 0, stream>>>(x, y, out);
}

// Round 2
// 451.345 us; speedup vs baseline: 1.0357x; 1.0357x over previous
//
#include <hip/hip_runtime.h>
#include <math.h>

// B=32, P=3, D=300, N=2048. Inputs x,y [B,P,D,N] f32; out [B,P*N,3] f32.
//
// R2 design: latency-bound fix. Each wave = 16 n-quads x 4 D-segments:
//   lane = s*16 + q;  q = n-quad (4 consecutive n, float4), s = D segment (75 rows).
// float4 loads -> 1 KB/wave/instr; unroll 5 -> ~10 KB in flight per wave,
// 12 waves/CU. Cross-segment reduce via 2 shfl_down steps; lanes 0..15 store.

constexpr int kB = 32;
constexpr int kP = 3;
constexpr int kD = 300;
constexpr int kN = 2048;
constexpr int kSeg = 4;           // D split factor
constexpr int kDSeg = kD / kSeg;  // 75 d-rows per segment

__device__ inline void reduce4(float4& v) {
    v.x += __shfl_down(v.x, 32); v.y += __shfl_down(v.y, 32);
    v.z += __shfl_down(v.z, 32); v.w += __shfl_down(v.w, 32);
    v.x += __shfl_down(v.x, 16); v.y += __shfl_down(v.y, 16);
    v.z += __shfl_down(v.z, 16); v.w += __shfl_down(v.w, 16);
}

__global__ __launch_bounds__(256) void sim_measure_kernel(
    const float* __restrict__ x,
    const float* __restrict__ y,
    float* __restrict__ out)
{
    const int tid  = blockIdx.x * 256 + threadIdx.x;
    const int lane = tid & 63;
    const int wave = tid >> 6;            // [0, B*P*N/64) = [0, 3072)

    const int q = lane & 15;              // n-quad index within wave's 64-n span
    const int s = lane >> 4;              // D segment [0,4)

    const int bp = wave >> 5;             // 32 waves per (b,p)
    const int n0 = (wave & 31) << 6;      // base n for this wave

    const size_t base = ((size_t)bp * kD + (size_t)s * kDSeg) * kN + (size_t)(n0 + q * 4);
    const float4* __restrict__ xp = (const float4*)(x + base);
    const float4* __restrict__ yp = (const float4*)(y + base);
    constexpr int kStride4 = kN / 4;      // 512 float4s between d-rows

    float4 dot = {0.f, 0.f, 0.f, 0.f};
    float4 xx  = {0.f, 0.f, 0.f, 0.f};
    float4 yy  = {0.f, 0.f, 0.f, 0.f};
    float4 l2s = {0.f, 0.f, 0.f, 0.f};
    float4 l1  = {0.f, 0.f, 0.f, 0.f};

    #pragma unroll 5
    for (int d = 0; d < kDSeg; ++d) {
        const float4 xv = xp[(size_t)d * kStride4];
        const float4 yv = yp[(size_t)d * kStride4];

        dot.x = fmaf(xv.x, yv.x, dot.x); dot.y = fmaf(xv.y, yv.y, dot.y);
        dot.z = fmaf(xv.z, yv.z, dot.z); dot.w = fmaf(xv.w, yv.w, dot.w);
        xx.x  = fmaf(xv.x, xv.x, xx.x);  xx.y  = fmaf(xv.y, xv.y, xx.y);
        xx.z  = fmaf(xv.z, xv.z, xx.z);  xx.w  = fmaf(xv.w, xv.w, xx.w);
        yy.x  = fmaf(yv.x, yv.x, yy.x);  yy.y  = fmaf(yv.y, yv.y, yy.y);
        yy.z  = fmaf(yv.z, yv.z, yy.z);  yy.w  = fmaf(yv.w, yv.w, yy.w);
        const float dx = xv.x - yv.x, dy = xv.y - yv.y,
                    dz = xv.z - yv.z, dw = xv.w - yv.w;
        l2s.x = fmaf(dx, dx, l2s.x); l2s.y = fmaf(dy, dy, l2s.y);
        l2s.z = fmaf(dz, dz, l2s.z); l2s.w = fmaf(dw, dw, l2s.w);
        l1.x += fabsf(dx); l1.y += fabsf(dy);
        l1.z += fabsf(dz); l1.w += fabsf(dw);
    }

    // Combine the 4 D-segments (lanes q, q+16, q+32, q+48) -> lanes 0..15
    reduce4(dot); reduce4(xx); reduce4(yy); reduce4(l2s); reduce4(l1);

    if (s == 0) {
        float4 o0, o1, o2;  // 12 floats: {cos,l2,l1} x 4 n
        const float c0 = dot.x / (sqrtf(xx.x) * sqrtf(yy.x));
        const float c1 = dot.y / (sqrtf(xx.y) * sqrtf(yy.y));
        const float c2 = dot.z / (sqrtf(xx.z) * sqrtf(yy.z));
        const float c3 = dot.w / (sqrtf(xx.w) * sqrtf(yy.w));
        const float e0 = sqrtf(l2s.x), e1 = sqrtf(l2s.y),
                    e2 = sqrtf(l2s.z), e3 = sqrtf(l2s.w);

        o0.x = c0;   o0.y = e0;   o0.z = l1.x; o0.w = c1;
        o1.x = e1;   o1.y = l1.y; o1.z = c2;   o1.w = e2;
        o2.x = l1.z; o2.y = c3;   o2.z = e3;   o2.w = l1.w;

        // out offset: (bp*N + n0 + q*4)*3 floats -> multiple of 12 -> 16B aligned
        float4* op = (float4*)(out + ((size_t)bp * kN + (size_t)(n0 + q * 4)) * 3);
        op[0] = o0; op[1] = o1; op[2] = o2;
    }
}

extern "C" void kernel_launch(void* const* d_in, const int* in_sizes, int n_in,
                              void* d_out, int out_size, void* d_ws, size_t ws_size,
                              hipStream_t stream)
{
    const float* x = (const float*)d_in[0];
    const float* y = (const float*)d_in[1];
    float* out = (float*)d_out;

    const int total = kB * kP * kN;                 // 196,608 threads (exact)
    const int block = 256;
    const int grid  = total / block;                // 768 blocks

    sim_measure_kernel<<<grid, block, 0, stream>>>(x, y, out);
}